// Round 16
// baseline (167.758 us; speedup 1.0000x reference)
//
#include <hip/hip_runtime.h>
#include <hip/hip_bf16.h>

#define B_ 32
#define S_ 64
#define H_ 300
#define H2_ 600
#define L_ 20
#define ROW_ 160                    // 8 pieces * 20
#define OUTQ_OFF ((size_t)B_ * S_ * ROW_)
#define NEG_INF -3.402823466e38f

typedef __attribute__((ext_vector_type(8))) _Float16 half8v;   // 8 f16 = 4 VGPRs
typedef __attribute__((ext_vector_type(4))) float float4v;

// ---------------- K1: cosine matrix + (prologue) w2t/w1 tables.
// Block = (bd, 16-row p-group); 256 blocks total, flat id covers 48000 w-elems.
__global__ __launch_bounds__(256) void k_cos(const float* __restrict__ P,
                                             const float* __restrict__ Q,
                                             const float* __restrict__ Wf,
                                             float* __restrict__ cosM,
                                             float* __restrict__ w2t,
                                             float* __restrict__ w1) {
  int bd = blockIdx.x;
  int pg = blockIdx.y;
  int p0 = pg * 16;
  int b = bd >> 1, dir = bd & 1;
  int t = threadIdx.x;
  {                                   // w-table prologue (one elem per thread)
    int i = (blockIdx.y * 64 + blockIdx.x) * 256 + t;
    if (i < 8 * L_ * H_) {
      float v = Wf[i];
      w1[i] = fabsf(v);
      int widx = i / (L_ * H_);
      int r = i - widx * (L_ * H_);
      int l = r / H_;
      int h = r - l * H_;
      w2t[widx * (L_ * H_) + h * L_ + l] = v * v;
    }
  }
  __shared__ float xp[16][101];
  __shared__ float xq[S_][101];
  __shared__ float pn[16], qn[S_];
  int q = t & 63, pr = t >> 6;
  float dot[4] = {0.f, 0.f, 0.f, 0.f};
  float np2 = 0.f, nq2 = 0.f;
  const float* Pb = P + (size_t)b * S_ * H2_ + dir * H_;
  const float* Qb = Q + (size_t)b * S_ * H2_ + dir * H_;
  for (int c0 = 0; c0 < H_; c0 += 100) {
    __syncthreads();
    for (int idx = t; idx < 16 * 100; idx += 256) {
      int s = idx / 100, hh = idx - s * 100;
      xp[s][hh] = Pb[(size_t)(p0 + s) * H2_ + c0 + hh];
    }
    for (int idx = t; idx < S_ * 100; idx += 256) {
      int s = idx / 100, hh = idx - s * 100;
      xq[s][hh] = Qb[(size_t)s * H2_ + c0 + hh];
    }
    __syncthreads();
    for (int hh = 0; hh < 100; ++hh) {
      float qv = xq[q][hh];
#pragma unroll
      for (int i = 0; i < 4; ++i) dot[i] = fmaf(xp[pr + 4 * i][hh], qv, dot[i]);
    }
    if (t < 16) {
      for (int hh = 0; hh < 100; ++hh) { float v = xp[t][hh]; np2 = fmaf(v, v, np2); }
    } else if (t >= 64 && t < 128) {
      int s2 = t - 64;
      for (int hh = 0; hh < 100; ++hh) { float v = xq[s2][hh]; nq2 = fmaf(v, v, nq2); }
    }
  }
  if (t < 16) pn[t] = sqrtf(np2);
  else if (t >= 64 && t < 128) qn[t - 64] = sqrtf(nq2);
  __syncthreads();
  float* cm = cosM + (size_t)bd * S_ * S_;
#pragma unroll
  for (int i = 0; i < 4; ++i) {
    int p = pr + 4 * i;
    cm[(size_t)(p0 + p) * S_ + q] = dot[i] / (pn[p] * qn[q]);   // no EPS (ref attentive)
  }
}

// ======== fused main kernel (r15 maxpool byte-identical; outs reworked) ========
#define HP 72
struct MaxpoolS {                   // ~21.4 KB
  _Float16 ph[S_][HP];
  _Float16 qh[S_][HP];
  float w1s[H_];
  float pn[S_], qn[S_];
  float colp[4][S_];
};
#define SG 4
struct OutsS {                      // 31264 B
  float u[600];                     // B: cosC[4][64]@0, cosR[4][64]@256; C: tq@0, tp@300
  float xP[SG][H_], xQ[SG][H_];
  float vmq[SG][H_], vmp[SG][H_], vxq[SG][H_], vxp[SG][H_];
  float sps[SG], sqs[SG];
};

__device__ __forceinline__ void maxpool_body(char* smem, int bid,
                                             const float* __restrict__ P,
                                             const float* __restrict__ Q,
                                             const float* __restrict__ w1,
                                             float* __restrict__ out) {
  MaxpoolS& S = *(MaxpoolS*)smem;
  int x = bid & 7, j = bid >> 3;           // XCD swizzle (r14)
  int bd = x + 8 * (j & 7);
  int l = j >> 3;
  int b = bd >> 1, dir = bd & 1;
  int t = threadIdx.x;
  int w = t >> 6, lane = t & 63, quad = lane >> 4, col = lane & 15;
  const float* w1g = w1 + (size_t)(2 + dir) * L_ * H_ + (size_t)l * H_;
  for (int idx = t; idx < H_; idx += 256) S.w1s[idx] = w1g[idx];
  const float* Pb = P + (size_t)b * S_ * H2_ + dir * H_;
  const float* Qb = Q + (size_t)b * S_ * H2_ + dir * H_;
  float4v acc[4];
#pragma unroll
  for (int qt = 0; qt < 4; ++qt) acc[qt] = (float4v){0.f, 0.f, 0.f, 0.f};
  float np2 = 0.f, nq2 = 0.f;
  for (int h0 = 0; h0 < H_; h0 += 64) {
    __syncthreads();
    for (int idx = t; idx < S_ * 64; idx += 256) {
      int s = idx >> 6, hh = idx & 63, h = h0 + hh;
      float pv = 0.f, qv = 0.f;
      if (h < H_) {
        float wv = S.w1s[h];
        pv = Pb[(size_t)s * H2_ + h] * wv;
        qv = Qb[(size_t)s * H2_ + h] * wv;
      }
      S.ph[s][hh] = (_Float16)pv;
      S.qh[s][hh] = (_Float16)qv;
    }
    __syncthreads();
#pragma unroll
    for (int ks = 0; ks < 2; ++ks) {
      half8v ah = *(const half8v*)&S.ph[16 * w + col][ks * 32 + quad * 8];
#pragma unroll
      for (int qt = 0; qt < 4; ++qt) {
        half8v bh = *(const half8v*)&S.qh[16 * qt + col][ks * 32 + quad * 8];
        acc[qt] = __builtin_amdgcn_mfma_f32_16x16x32_f16(ah, bh, acc[qt], 0, 0, 0);
      }
    }
    if (t < S_) {
      for (int hh = 0; hh < 64; ++hh) {
        float v = (float)S.ph[t][hh];
        np2 = fmaf(v, v, np2);
      }
    } else if (t < 2 * S_) {
      int s2 = t - S_;
      for (int hh = 0; hh < 64; ++hh) {
        float v = (float)S.qh[s2][hh];
        nq2 = fmaf(v, v, nq2);
      }
    }
  }
  if (t < S_) S.pn[t] = sqrtf(np2);
  else if (t < 2 * S_) S.qn[t - S_] = sqrtf(nq2);
  __syncthreads();
  float pnv[4];
#pragma unroll
  for (int r = 0; r < 4; ++r) pnv[r] = S.pn[16 * w + quad * 4 + r];
  float rowm[4] = {NEG_INF, NEG_INF, NEG_INF, NEG_INF};
#pragma unroll
  for (int qt = 0; qt < 4; ++qt) {
    float qnv = S.qn[16 * qt + col];
    float cm = NEG_INF;
#pragma unroll
    for (int r = 0; r < 4; ++r) {
      float c = acc[qt][r] / (pnv[r] * qnv);    // no EPS in reference maxpool
      rowm[r] = fmaxf(rowm[r], c);
      cm = fmaxf(cm, c);
    }
    cm = fmaxf(cm, __shfl_xor(cm, 16));
    cm = fmaxf(cm, __shfl_xor(cm, 32));
    if (quad == 0) S.colp[w][16 * qt + col] = cm;
  }
#pragma unroll
  for (int m = 1; m < 16; m <<= 1)
#pragma unroll
    for (int r = 0; r < 4; ++r) rowm[r] = fmaxf(rowm[r], __shfl_xor(rowm[r], m));
  if (col == 0) {
#pragma unroll
    for (int r = 0; r < 4; ++r) {
      int p = 16 * w + quad * 4 + r;
      out[((size_t)b * S_ + p) * ROW_ + (2 + dir) * L_ + l] = rowm[r];
    }
  }
  __syncthreads();
  if (t < S_) {
    float m0 = fmaxf(fmaxf(S.colp[0][t], S.colp[1][t]), fmaxf(S.colp[2][t], S.colp[3][t]));
    out[OUTQ_OFF + ((size_t)b * S_ + t) * ROW_ + (2 + dir) * L_ + l] = m0;
  }
}

__device__ __forceinline__ void outs_body(char* smem, int bid,
                                          const float* __restrict__ P,
                                          const float* __restrict__ Q,
                                          const float* __restrict__ w2t,
                                          const float* __restrict__ cosM,
                                          float* __restrict__ out) {
  OutsS& S = *(OutsS*)smem;
  int x = bid & 7, j = bid >> 3;           // XCD swizzle
  int bd = x + 8 * (j & 7);
  int sg = j >> 3;
  int s0 = sg * SG;
  int b = bd >> 1, dir = bd & 1;
  int t = threadIdx.x;
  float (*cosC)[S_] = (float (*)[S_])&S.u[0];
  float (*cosR)[S_] = (float (*)[S_])&S.u[256];
  const float* cm = cosM + (size_t)bd * S_ * S_;
  for (int idx = t; idx < SG * S_; idx += 256) {
    int si = idx >> 6, k = idx & 63;
    cosC[si][k] = cm[k * S_ + s0 + si];
    cosR[si][k] = cm[(s0 + si) * S_ + k];
  }
  int tgt = dir ? 0 : S_ - 1;
  const float* Pb = P + (size_t)b * S_ * H2_ + dir * H_;
  const float* Qb = Q + (size_t)b * S_ * H2_ + dir * H_;
  for (int idx = t; idx < SG * H_; idx += 256) {
    int si = idx / H_, h = idx - si * H_;
    S.xP[si][h] = Pb[(size_t)(s0 + si) * H2_ + h];
    S.xQ[si][h] = Qb[(size_t)(s0 + si) * H2_ + h];
  }
  __syncthreads();
  // sps/sqs computed locally (r16): sps = sum_p cos[p][s] = sum_k cosC; sqs = sum_k cosR.
  if (t < 2 * SG) {
    int si = t & (SG - 1);
    const float* row = (t >= SG) ? cosR[si] : cosC[si];
    float acc = 0.f;
    for (int k = 0; k < S_; ++k) acc += row[k];
    if (t >= SG) S.sqs[si] = acc; else S.sps[si] = acc;
  }
  __syncthreads();
  // Phase B: attention vectors for 4 s values
  for (int h = t; h < H_; h += 256) {
    float amp[SG], amq[SG], axp[SG], axq[SG];
#pragma unroll
    for (int si = 0; si < SG; ++si) { amp[si] = 0.f; amq[si] = 0.f; axp[si] = NEG_INF; axq[si] = NEG_INF; }
    for (int k = 0; k < S_; k += 2) {
      float pv0 = Pb[(size_t)k * H2_ + h];
      float qv0 = Qb[(size_t)k * H2_ + h];
      float pv1 = Pb[(size_t)(k + 1) * H2_ + h];
      float qv1 = Qb[(size_t)(k + 1) * H2_ + h];
#pragma unroll
      for (int si = 0; si < SG; ++si) {
        float t1 = pv0 * cosC[si][k];
        amp[si] += t1; axp[si] = fmaxf(axp[si], t1);
        float t2 = qv0 * cosR[si][k];
        amq[si] += t2; axq[si] = fmaxf(axq[si], t2);
        float t3 = pv1 * cosC[si][k + 1];
        amp[si] += t3; axp[si] = fmaxf(axp[si], t3);
        float t4 = qv1 * cosR[si][k + 1];
        amq[si] += t4; axq[si] = fmaxf(axq[si], t4);
      }
    }
#pragma unroll
    for (int si = 0; si < SG; ++si) {
      S.vmq[si][h] = amq[si] / S.sqs[si];
      S.vmp[si][h] = amp[si] / S.sps[si];
      S.vxq[si][h] = axq[si];
      S.vxp[si][h] = axp[si];
    }
  }
  __syncthreads();
  float* tq = &S.u[0];
  float* tp = &S.u[300];
  for (int h = t; h < H_; h += 256) { tq[h] = Qb[(size_t)tgt * H2_ + h]; tp[h] = Pb[(size_t)tgt * H2_ + h]; }
  __syncthreads();
  // Phase C (r16): thread t<240 fuses its 2 jobs (same l, same pr, si0 & si0+2):
  // one shared w2t stream, two independent accumulator chains.
  if (t < 240) {
    int l = t % L_;
    int g = t / L_;            // 0..11
    int pr = g % 6, si0 = g / 6;   // si0 in {0,1}; jobs use si0 and si0+2
    int si1 = si0 + 2;
    const float* x0 = (pr & 1) ? S.xQ[si0] : S.xP[si0];
    const float* x1 = (pr & 1) ? S.xQ[si1] : S.xP[si1];
    const float* y0;
    const float* y1;
    if (pr == 0)      { y0 = tq;         y1 = tq; }
    else if (pr == 1) { y0 = tp;         y1 = tp; }
    else if (pr == 2) { y0 = S.vmq[si0]; y1 = S.vmq[si1]; }
    else if (pr == 3) { y0 = S.vmp[si0]; y1 = S.vmp[si1]; }
    else if (pr == 4) { y0 = S.vxq[si0]; y1 = S.vxq[si1]; }
    else              { y0 = S.vxp[si0]; y1 = S.vxp[si1]; }
    const int wb_[6] = {0, 0, 4, 4, 6, 6};
    int widx = wb_[pr] + dir;
    const float* wp = w2t + (size_t)widx * (L_ * H_) + l;
    float a1_0 = 0.f, a2_0 = 0.f, a3_0 = 0.f;
    float a1_1 = 0.f, a2_1 = 0.f, a3_1 = 0.f;
    for (int h = 0; h < H_; ++h) {
      float wv = wp[h * L_];
      float xx0 = x0[h], yy0 = y0[h];
      float xx1 = x1[h], yy1 = y1[h];
      float wx0 = wv * xx0, wx1 = wv * xx1;
      a1_0 = fmaf(wx0, yy0, a1_0);
      a2_0 = fmaf(wx0, xx0, a2_0);
      a3_0 = fmaf(wv * yy0, yy0, a3_0);
      a1_1 = fmaf(wx1, yy1, a1_1);
      a2_1 = fmaf(wx1, xx1, a2_1);
      a3_1 = fmaf(wv * yy1, yy1, a3_1);
    }
    float den0 = fmaxf(sqrtf(a2_0) * sqrtf(a3_0), 1e-8f);   // EPS per _mp_cos
    float den1 = fmaxf(sqrtf(a2_1) * sqrtf(a3_1), 1e-8f);
    float c0 = a1_0 / den0;
    float c1 = a1_1 / den1;
    size_t pb = ((pr & 1) ? OUTQ_OFF : 0);
    out[pb + ((size_t)b * S_ + s0 + si0) * ROW_ + (size_t)widx * L_ + l] = c0;
    out[pb + ((size_t)b * S_ + s0 + si1) * ROW_ + (size_t)widx * L_ + l] = c1;
  }
}

__global__ __launch_bounds__(256) void k_main(const float* __restrict__ P,
                                              const float* __restrict__ Q,
                                              const float* __restrict__ w1,
                                              const float* __restrict__ w2t,
                                              const float* __restrict__ cosM,
                                              float* __restrict__ out) {
  extern __shared__ char smem[];
  int bid = blockIdx.x;
  if (bid < B_ * 2 * L_) maxpool_body(smem, bid, P, Q, w1, out);
  else outs_body(smem, bid - B_ * 2 * L_, P, Q, w2t, cosM, out);
}

extern "C" void kernel_launch(void* const* d_in, const int* in_sizes, int n_in,
                              void* d_out, int out_size, void* d_ws, size_t ws_size,
                              hipStream_t stream) {
  (void)out_size; (void)ws_size;
  int iw = 2;
  for (int i = 0; i < n_in; ++i) if (in_sizes[i] == 8 * L_ * H_) iw = i;
  int io[2] = {0, 1}, k = 0;
  for (int i = 0; i < n_in && k < 2; ++i) if (i != iw) io[k++] = i;
  const float* P  = (const float*)d_in[io[0]];
  const float* Q  = (const float*)d_in[io[1]];
  const float* Wf = (const float*)d_in[iw];
  float* out = (float*)d_out;

  float* ws = (float*)d_ws;         // ~1.43 MB
  float* w2t   = ws;                // 48000
  float* w1    = w2t + 48000;       // 48000
  float* cosM  = w1 + 48000;        // 262144

  size_t shbytes = sizeof(MaxpoolS) > sizeof(OutsS) ? sizeof(MaxpoolS) : sizeof(OutsS);
  k_cos<<<dim3(B_ * 2, 4), 256, 0, stream>>>(P, Q, Wf, cosM, w2t, w1);
  k_main<<<B_ * 2 * L_ + B_ * 2 * 16, 256, shbytes, stream>>>(P, Q, w1, w2t, cosM, out);
}